// Round 1
// baseline (25.566 us; speedup 1.0000x reference)
//
#include <hip/hip_runtime.h>

// Problem constants (match reference)
#define BATCH 32
#define CH    2
#define HH    224
#define WW    224
#define PP    4096
#define NN    256
#define SPLIT 8
#define TILE  (PP / SPLIT)   // 512 points per block

// Kernel A: one block per (batch, point-tile). 256 threads, one per pair n.
// Each thread:
//   1. recomputes Y[n] (cheap: 8 gathers + 2x2 pinv solve in double)
//   2. counts agreement votes over this block's 512-point tile (LDS broadcast)
//   3. block tree-reduce of (w*Yy, w*Yx, w) -> partial accumulators in ws
__global__ __launch_bounds__(256)
void hough_partial(const float* __restrict__ uv,
                   const int* __restrict__ pts,
                   const int* __restrict__ pair,
                   double* __restrict__ part)
{
    const int blk = blockIdx.x;
    const int b = blk / SPLIT;
    const int s = blk % SPLIT;
    const int t = threadIdx.x;   // n = t

    const float* uvb = uv + (size_t)b * CH * HH * WW;   // channel stride HH*WW
    const int* ptsb = pts + b * PP * 2;

    // ---- per-pair solve: Y[n] ----
    const int i0 = pair[(b * NN + t) * 2 + 0];
    const int i1 = pair[(b * NN + t) * 2 + 1];
    const int y0 = ptsb[i0 * 2 + 0], x0 = ptsb[i0 * 2 + 1];
    const int y1 = ptsb[i1 * 2 + 0], x1 = ptsb[i1 * 2 + 1];

    const float u0a = uvb[y0 * WW + x0];                 // uv[0] at pt0
    const float u0b = uvb[HH * WW + y0 * WW + x0];       // uv[1] at pt0
    const float u1a = uvb[y1 * WW + x1];                 // uv[0] at pt1
    const float u1b = uvb[HH * WW + y1 * WW + x1];       // uv[1] at pt1

    // A = [[u0a, -u1a], [u0b, -u1b]], bv = (y1-y0, x1-x0); want x0 of pinv(A)@bv
    const double a00 = (double)u0a, a01 = -(double)u1a;
    const double a10 = (double)u0b, a11 = -(double)u1b;
    const double b0 = (double)(y1 - y0), b1 = (double)(x1 - x0);
    const double det = a00 * a11 - a01 * a10;
    const double frob2 = a00 * a00 + a01 * a01 + a10 * a10 + a11 * a11;

    double t0;
    if (fabs(det) > 1e-12 * frob2) {
        t0 = (b0 * a11 - b1 * a01) / det;          // first row of A^{-1} b
    } else if (frob2 > 0.0) {
        t0 = (a00 * b0 + a10 * b1) / frob2;        // rank-1 pinv: A^T b / ||A||_F^2
    } else {
        t0 = 0.0;
    }

    const float yy = (float)(t0 * (double)u0a + (double)y0);  // Y comp0 (row)
    const float yx = (float)(t0 * (double)u0b + (double)x0);  // Y comp1 (col)

    // ---- stage this block's point tile in LDS ----
    __shared__ float4 tile[TILE];                 // (py, px, uv0, uv1)
    for (int j = t; j < TILE; j += 256) {
        const int p = s * TILE + j;
        const int py = ptsb[p * 2 + 0], px = ptsb[p * 2 + 1];
        const float pu = uvb[py * WW + px];
        const float pv = uvb[HH * WW + py * WW + px];
        tile[j] = make_float4((float)py, (float)px, pu, pv);
    }
    __syncthreads();

    // ---- voting: sign of (Y - p) . uv(p)  (normalization can't flip sign) ----
    int cnt = 0;
    #pragma unroll 8
    for (int j = 0; j < TILE; ++j) {
        const float4 q = tile[j];                 // same addr all lanes: broadcast
        const float dy = yy - q.x;
        const float dx = yx - q.y;
        const float dot = dy * q.z + dx * q.w;
        cnt += (dot > 0.0f) ? 1 : 0;
    }

    // ---- deterministic block reduction of (w*Yy, w*Yx, w) in double ----
    const double w = (double)cnt;
    __shared__ double red[3 * 256];
    red[t]       = w * (double)yy;
    red[256 + t] = w * (double)yx;
    red[512 + t] = w;
    __syncthreads();
    for (int off = 128; off > 0; off >>= 1) {
        if (t < off) {
            red[t]       += red[t + off];
            red[256 + t] += red[256 + t + off];
            red[512 + t] += red[512 + t + off];
        }
        __syncthreads();
    }
    if (t == 0) {
        double* o = part + (size_t)(b * SPLIT + s) * 4;
        o[0] = red[0];
        o[1] = red[256];
        o[2] = red[512];
    }
}

// Kernel B: combine the SPLIT partials per batch, divide, write reversed output.
__global__ __launch_bounds__(64)
void hough_final(const double* __restrict__ part, float* __restrict__ out)
{
    const int b = threadIdx.x;
    if (b < BATCH) {
        double sy = 0.0, sx = 0.0, sw = 0.0;
        for (int s = 0; s < SPLIT; ++s) {
            const double* o = part + (size_t)(b * SPLIT + s) * 4;
            sy += o[0];
            sx += o[1];
            sw += o[2];
        }
        // weighted_mean = (sy/sw, sx/sw) in (row, col); output is [::-1]
        out[b * 2 + 0] = (float)(sx / sw);
        out[b * 2 + 1] = (float)(sy / sw);
    }
}

extern "C" void kernel_launch(void* const* d_in, const int* in_sizes, int n_in,
                              void* d_out, int out_size, void* d_ws, size_t ws_size,
                              hipStream_t stream)
{
    const float* uv   = (const float*)d_in[0];   // (B, 2, 224, 224) f32
    const int*   pts  = (const int*)d_in[1];     // (B, 4096, 2) i32
    const int*   pair = (const int*)d_in[2];     // (B, 256, 2) i32
    float* out = (float*)d_out;                  // (B, 2) f32
    double* part = (double*)d_ws;                // BATCH*SPLIT*4 doubles = 8 KB

    hough_partial<<<BATCH * SPLIT, 256, 0, stream>>>(uv, pts, pair, part);
    hough_final<<<1, 64, 0, stream>>>(part, out);
}

// Round 2
// 24.377 us; speedup vs baseline: 1.0488x; 1.0488x over previous
//
#include <hip/hip_runtime.h>

// Problem constants (match reference)
#define BATCH 32
#define CH    2
#define HH    224
#define WW    224
#define PP    4096
#define NN    256
#define SPLIT 32
#define TILE  (PP / SPLIT)   // 128 points per block

// Kernel A: one block per (batch, point-tile). 256 threads, one per pair n.
//   1. recompute Y[n] (8 L2-cached gathers + analytic 2x2 pinv in double)
//   2. count agreement votes over this block's 128-point tile (LDS broadcast)
//   3. wave-shuffle reduce (w*Yy, w*Yx, w) -> per-block partial in ws
__global__ __launch_bounds__(256)
void hough_partial(const float* __restrict__ uv,
                   const int* __restrict__ pts,
                   const int* __restrict__ pair,
                   double* __restrict__ part)
{
    const int blk = blockIdx.x;
    const int b = blk / SPLIT;
    const int s = blk % SPLIT;
    const int t = threadIdx.x;   // n = t

    const float* uvb = uv + (size_t)b * CH * HH * WW;   // channel stride HH*WW
    const int* ptsb = pts + b * PP * 2;

    // ---- stage this block's point tile in LDS (do the loads first so the
    //      gathers overlap with the per-pair solve below) ----
    __shared__ float4 tile[TILE];                 // (py, px, uv0, uv1)
    if (t < TILE) {
        const int p = s * TILE + t;
        const int2 pyx = *(const int2*)(ptsb + p * 2);   // coalesced 8B
        const float pu = uvb[pyx.x * WW + pyx.y];
        const float pv = uvb[HH * WW + pyx.x * WW + pyx.y];
        tile[t] = make_float4((float)pyx.x, (float)pyx.y, pu, pv);
    }

    // ---- per-pair solve: Y[n] ----
    const int2 pr = *(const int2*)(pair + (b * NN + t) * 2);
    const int2 p0 = *(const int2*)(ptsb + pr.x * 2);
    const int2 p1 = *(const int2*)(ptsb + pr.y * 2);
    const int y0 = p0.x, x0 = p0.y;
    const int y1 = p1.x, x1 = p1.y;

    const float u0a = uvb[y0 * WW + x0];                 // uv[0] at pt0
    const float u0b = uvb[HH * WW + y0 * WW + x0];       // uv[1] at pt0
    const float u1a = uvb[y1 * WW + x1];                 // uv[0] at pt1
    const float u1b = uvb[HH * WW + y1 * WW + x1];       // uv[1] at pt1

    // A = [[u0a, -u1a], [u0b, -u1b]], bv = (y1-y0, x1-x0); want row0 of pinv(A)@bv
    const double a00 = (double)u0a, a01 = -(double)u1a;
    const double a10 = (double)u0b, a11 = -(double)u1b;
    const double b0 = (double)(y1 - y0), b1 = (double)(x1 - x0);
    const double det = a00 * a11 - a01 * a10;
    const double frob2 = a00 * a00 + a01 * a01 + a10 * a10 + a11 * a11;

    double t0;
    if (fabs(det) > 1e-12 * frob2) {
        t0 = (b0 * a11 - b1 * a01) / det;          // first row of A^{-1} b
    } else if (frob2 > 0.0) {
        t0 = (a00 * b0 + a10 * b1) / frob2;        // rank-1 pinv: A^T b / ||A||_F^2
    } else {
        t0 = 0.0;
    }

    const float yy = (float)(t0 * (double)u0a + (double)y0);  // Y comp0 (row)
    const float yx = (float)(t0 * (double)u0b + (double)x0);  // Y comp1 (col)

    __syncthreads();

    // ---- voting: sign of (Y - p) . uv(p)  (normalization can't flip sign) ----
    int cnt = 0;
    #pragma unroll 8
    for (int j = 0; j < TILE; ++j) {
        const float4 q = tile[j];                 // same addr all lanes: broadcast
        const float dy = yy - q.x;
        const float dx = yx - q.y;
        const float dot = dy * q.z + dx * q.w;
        cnt += (dot > 0.0f) ? 1 : 0;
    }

    // ---- deterministic reduction of (w*Yy, w*Yx, w): wave shuffles, then
    //      one barrier + 4-way combine ----
    double wy = (double)cnt * (double)yy;
    double wx = (double)cnt * (double)yx;
    double ww = (double)cnt;
    #pragma unroll
    for (int off = 32; off > 0; off >>= 1) {
        wy += __shfl_down(wy, off);
        wx += __shfl_down(wx, off);
        ww += __shfl_down(ww, off);
    }

    __shared__ double red[4 * 3];
    const int wid = t >> 6;
    if ((t & 63) == 0) {
        red[wid * 3 + 0] = wy;
        red[wid * 3 + 1] = wx;
        red[wid * 3 + 2] = ww;
    }
    __syncthreads();
    if (t == 0) {
        double sy = red[0] + red[3] + red[6] + red[9];
        double sx = red[1] + red[4] + red[7] + red[10];
        double sw = red[2] + red[5] + red[8] + red[11];
        double* o = part + (size_t)(b * SPLIT + s) * 4;
        o[0] = sy;
        o[1] = sx;
        o[2] = sw;
    }
}

// Kernel B: combine the SPLIT partials per batch, divide, write reversed output.
__global__ __launch_bounds__(64)
void hough_final(const double* __restrict__ part, float* __restrict__ out)
{
    const int b = threadIdx.x;
    if (b < BATCH) {
        double sy = 0.0, sx = 0.0, sw = 0.0;
        for (int s = 0; s < SPLIT; ++s) {
            const double* o = part + (size_t)(b * SPLIT + s) * 4;
            sy += o[0];
            sx += o[1];
            sw += o[2];
        }
        // weighted_mean = (sy/sw, sx/sw) in (row, col); output is [::-1]
        out[b * 2 + 0] = (float)(sx / sw);
        out[b * 2 + 1] = (float)(sy / sw);
    }
}

extern "C" void kernel_launch(void* const* d_in, const int* in_sizes, int n_in,
                              void* d_out, int out_size, void* d_ws, size_t ws_size,
                              hipStream_t stream)
{
    const float* uv   = (const float*)d_in[0];   // (B, 2, 224, 224) f32
    const int*   pts  = (const int*)d_in[1];     // (B, 4096, 2) i32
    const int*   pair = (const int*)d_in[2];     // (B, 256, 2) i32
    float* out = (float*)d_out;                  // (B, 2) f32
    double* part = (double*)d_ws;                // BATCH*SPLIT*4 doubles = 32 KB

    hough_partial<<<BATCH * SPLIT, 256, 0, stream>>>(uv, pts, pair, part);
    hough_final<<<1, 64, 0, stream>>>(part, out);
}

// Round 4
// 22.114 us; speedup vs baseline: 1.1561x; 1.1023x over previous
//
#include <hip/hip_runtime.h>
#include <hip/hip_fp16.h>

// Problem constants (match reference)
#define BATCH 32
#define CH    2
#define HH    224
#define WW    224
#define PP    4096
#define NN    256
#define SPLIT 32
#define TILE  (PP / SPLIT)   // 128 points per block
#define TILE2 (TILE / 2)     // 64 packed point-pairs

// Packed vote-point pair: (u0,u1),(v0,v1),(-c0,-c1) in f16, padded to 16B so
// the vote loop reads one ds_read_b128 per TWO points. c = py*u + px*v, so
// agree = sign(yy*u + yx*v - c)  (normalization in the reference can't flip
// the sign, so the norm is dropped).
struct alignas(16) PtPack { __half2 u, v, nc, pad; };

// Kernel A: one block per (batch, point-tile). 256 threads, one per pair n.
//   1. stage TILE points as f16 PtPacks in LDS (gathers overlap the solve)
//   2. per-pair 2x2 pinv solve in f64 -> Y[n]; scale n-side vector (yy,yx,1)
//      by s = min(1, 1024/max|Y|) so every f16 product stays finite
//   3. packed-f16 vote over the tile, sign-bit counting
//   4. wave-shuffle reduce (w*Yy, w*Yx, w) -> per-block partial in ws
__global__ __launch_bounds__(256, 4)
void hough_partial(const float* __restrict__ uv,
                   const int* __restrict__ pts,
                   const int* __restrict__ pair,
                   double* __restrict__ part)
{
    const int blk = blockIdx.x;
    const int b = blk / SPLIT;
    const int s = blk % SPLIT;
    const int t = threadIdx.x;   // n = t

    const float* uvb = uv + (size_t)b * CH * HH * WW;   // channel stride HH*WW
    const int* ptsb = pts + b * PP * 2;

    // ---- stage this block's point tile in LDS (f16-packed, 2 pts / 16B) ----
    __shared__ PtPack tile[TILE2];
    if (t < TILE2) {
        const int p = s * TILE + 2 * t;
        const int4 pp = *(const int4*)(ptsb + p * 2);   // (y0,x0,y1,x1), 16B
        const float u0 = uvb[pp.x * WW + pp.y];
        const float v0 = uvb[HH * WW + pp.x * WW + pp.y];
        const float u1 = uvb[pp.z * WW + pp.w];
        const float v1 = uvb[HH * WW + pp.z * WW + pp.w];
        const float c0 = (float)pp.x * u0 + (float)pp.y * v0;
        const float c1 = (float)pp.z * u1 + (float)pp.w * v1;
        PtPack pk;
        pk.u  = __floats2half2_rn(u0, u1);
        pk.v  = __floats2half2_rn(v0, v1);
        pk.nc = __floats2half2_rn(-c0, -c1);
        pk.pad = __floats2half2_rn(0.0f, 0.0f);
        tile[t] = pk;
    }

    // ---- per-pair solve: Y[n] (f64, matches pinv semantics) ----
    const int2 pr = *(const int2*)(pair + (b * NN + t) * 2);
    const int2 p0 = *(const int2*)(ptsb + pr.x * 2);
    const int2 p1 = *(const int2*)(ptsb + pr.y * 2);
    const int y0 = p0.x, x0 = p0.y;
    const int y1 = p1.x, x1 = p1.y;

    const float u0a = uvb[y0 * WW + x0];                 // uv[0] at pt0
    const float u0b = uvb[HH * WW + y0 * WW + x0];       // uv[1] at pt0
    const float u1a = uvb[y1 * WW + x1];                 // uv[0] at pt1
    const float u1b = uvb[HH * WW + y1 * WW + x1];       // uv[1] at pt1

    const double a00 = (double)u0a, a01 = -(double)u1a;
    const double a10 = (double)u0b, a11 = -(double)u1b;
    const double b0 = (double)(y1 - y0), b1 = (double)(x1 - x0);
    const double det = a00 * a11 - a01 * a10;
    const double frob2 = a00 * a00 + a01 * a01 + a10 * a10 + a11 * a11;

    double t0;
    if (fabs(det) > 1e-12 * frob2) {
        t0 = (b0 * a11 - b1 * a01) / det;          // first row of A^{-1} b
    } else if (frob2 > 0.0) {
        t0 = (a00 * b0 + a10 * b1) / frob2;        // rank-1 pinv: A^T b / ||A||_F^2
    } else {
        t0 = 0.0;
    }

    const float yy = (float)(t0 * (double)u0a + (double)y0);  // Y comp0 (row)
    const float yx = (float)(t0 * (double)u0b + (double)x0);  // Y comp1 (col)

    // ---- scale the n-side vector (yy, yx, 1) into f16-safe range ----
    const float maxab = fmaxf(fabsf(yy), fabsf(yx));
    const float sc = (maxab > 1024.0f) ? (1024.0f / maxab) : 1.0f;
    const __half2 yy2 = __float2half2_rn(yy * sc);
    const __half2 yx2 = __float2half2_rn(yx * sc);
    const __half2 sc2 = __float2half2_rn(sc);

    __syncthreads();

    // ---- voting: packed f16, 2 points per iteration, sign-bit counting ----
    // negs accumulates two 16-bit lane counters (lo half = even pts, hi = odd).
    unsigned negs = 0u;
    #pragma unroll 4
    for (int j = 0; j < TILE2; ++j) {
        const PtPack q = tile[j];                  // broadcast ds_read_b128
        __half2 d = __hmul2(yy2, q.u);
        d = __hfma2(yx2, q.v, d);
        d = __hfma2(sc2, q.nc, d);
        unsigned ub;
        __builtin_memcpy(&ub, &d, 4);
        negs += (ub >> 15) & 0x00010001u;          // sign bits of both halves
    }
    const int cnt = TILE - (int)(negs & 0xFFFFu) - (int)(negs >> 16);

    // ---- deterministic reduction of (w*Yy, w*Yx, w): wave shuffles, then
    //      one barrier + 4-way combine ----
    double wy = (double)cnt * (double)yy;
    double wx = (double)cnt * (double)yx;
    double ww = (double)cnt;
    #pragma unroll
    for (int off = 32; off > 0; off >>= 1) {
        wy += __shfl_down(wy, off);
        wx += __shfl_down(wx, off);
        ww += __shfl_down(ww, off);
    }

    __shared__ double red[4 * 3];
    const int wid = t >> 6;
    if ((t & 63) == 0) {
        red[wid * 3 + 0] = wy;
        red[wid * 3 + 1] = wx;
        red[wid * 3 + 2] = ww;
    }
    __syncthreads();
    if (t == 0) {
        double* o = part + (size_t)blk * 4;
        o[0] = red[0] + red[3] + red[6] + red[9];
        o[1] = red[1] + red[4] + red[7] + red[10];
        o[2] = red[2] + red[5] + red[8] + red[11];
    }
}

// Kernel B: combine the SPLIT partials per batch, divide, write reversed out.
// 256 threads = 32 batches x 8 lanes; each lane sums 4 partials, then a
// 3-step shfl_xor butterfly within the aligned 8-lane group.
__global__ __launch_bounds__(256)
void hough_final(const double* __restrict__ part, float* __restrict__ out)
{
    const int t = threadIdx.x;
    const int bb = t >> 3;
    const int l8 = t & 7;
    double sy = 0.0, sx = 0.0, sw = 0.0;
    #pragma unroll
    for (int k = l8; k < SPLIT; k += 8) {
        const double* o = part + (size_t)(bb * SPLIT + k) * 4;
        sy += o[0];
        sx += o[1];
        sw += o[2];
    }
    #pragma unroll
    for (int off = 1; off < 8; off <<= 1) {
        sy += __shfl_xor(sy, off);
        sx += __shfl_xor(sx, off);
        sw += __shfl_xor(sw, off);
    }
    if (l8 == 0) {
        // weighted_mean = (sy/sw, sx/sw) in (row, col); output is [::-1]
        out[bb * 2 + 0] = (float)(sx / sw);
        out[bb * 2 + 1] = (float)(sy / sw);
    }
}

extern "C" void kernel_launch(void* const* d_in, const int* in_sizes, int n_in,
                              void* d_out, int out_size, void* d_ws, size_t ws_size,
                              hipStream_t stream)
{
    const float* uv   = (const float*)d_in[0];   // (B, 2, 224, 224) f32
    const int*   pts  = (const int*)d_in[1];     // (B, 4096, 2) i32
    const int*   pair = (const int*)d_in[2];     // (B, 256, 2) i32
    float* out = (float*)d_out;                  // (B, 2) f32
    double* part = (double*)d_ws;                // BATCH*SPLIT*4 doubles = 32 KB

    hough_partial<<<BATCH * SPLIT, 256, 0, stream>>>(uv, pts, pair, part);
    hough_final<<<1, 256, 0, stream>>>(part, out);
}